// Round 11
// baseline (1245.168 us; speedup 1.0000x reference)
//
#include <hip/hip_runtime.h>
#include <hip/hip_bf16.h>

// HunyuanTopKGate: x[4096,4096] fp32, wg[64,4096] fp32 ->
//   combine_weights [T,E,C] fp32 ++ dispatch_mask [T,E,C] (as fp32 0/1)
// C = out_size/(2*T*E) = 2268 -> 4.76 GB output zero-fill (~765us at the
// 6.2 TB/s fill ceiling) is the roofline pole.
//
// Round 11: R10 tail accounting (1237-760 = 477 = 40+5+405+15+12) proves
// verify tripped on the bf16x3 MFMA gemm and the fp64 repair ran. Numerics
// have 100x margin (err ~1e-5 vs tol 1e-3), A-frag (m120) and C/D (m89/91)
// are HW-pinned -> the unverified binary is the MFMA A/B ARGUMENT-ROLE
// convention. This round cascades both: V0 = mfma(a,b) with D[row=token],
// V1 (gated on V0's verify failing) = mfma(b,a) with D[row=expert,
// col=token]. Verify after each; fp64 split-K repair as final net.
// dur diagnoses the winner: ~865 V0 / ~920 V1 / ~1250 both-wrong.
//
// ws: partial[8][4096][64] f64 (16MB) | idx_kt | w_kt | flagA | flagB

#define TOK 4096
#define HID 4096
#define NE  64
#define NK  8

typedef __attribute__((ext_vector_type(8))) short short8;   // 8 bf16
typedef __attribute__((ext_vector_type(4))) float f32x4;

__device__ __forceinline__ short f2bf(float f) {
  __hip_bfloat16 h = __float2bfloat16(f);   // RNE
  return *reinterpret_cast<short*>(&h);
}
__device__ __forceinline__ float bf2f(short s) {
  unsigned u = ((unsigned)(unsigned short)s) << 16;
  return __uint_as_float(u);
}
__device__ __forceinline__ void cvt3(float f, short& s0, short& s1, short& s2) {
  s0 = f2bf(f);
  float r1 = f - bf2f(s0);
  s1 = f2bf(r1);
  float r2 = r1 - bf2f(s1);
  s2 = f2bf(r2);
}

// ---------------- 1. bf16x3 MFMA GEMM (arg-order selectable) -------------
// Grid (64 token-tiles, nsplit k-slabs), 256 thr = 4 waves.
// Block: 64 tokens x 64 experts x kchunk. Wave w: token rows w*16..+15,
// 4 expert 16-col tiles. x-frag: lane holds X[t=w*16+(lane&15)][k=q*8+j];
// wg-frag: lane holds Wg[e=nt*16+(lane&15)][k=q*8+j]  (wg is [E][K]=B^T).
// swap=0: D=mfma(xf,wf): row(q*4+v)=token, col(lane&15)=expert.
// swap=1: D=mfma(wf,xf): row(q*4+v)=expert, col(lane&15)=token.
// gate: if non-null and *gate==0, whole kernel early-outs (~3us).
__global__ __launch_bounds__(256) void gemm_bf16x3(
    const float* __restrict__ x, const float* __restrict__ wg,
    double* __restrict__ partial, int kchunk, int swap,
    const int* __restrict__ gate, int* __restrict__ clr0,
    int* __restrict__ clr1) {
  if (gate && *(volatile const int*)gate == 0) return;
  __shared__ __align__(16) short XA[3][64][72];   // 27.6 KB
  __shared__ __align__(16) short WB[3][64][72];   // 27.6 KB
  const int tid = threadIdx.x;
  if (blockIdx.x == 0 && blockIdx.y == 0 && tid == 0) {
    if (clr0) *clr0 = 0;
    if (clr1) *clr1 = 0;
  }
  const int t0   = blockIdx.x * 64;
  const int k0   = blockIdx.y * kchunk;
  const int lane = tid & 63;
  const int w    = tid >> 6;
  const int m    = lane & 15;       // frag row/col within 16
  const int q    = lane >> 4;       // quad
  const int lrow = tid >> 2;        // staging: 4 threads per row
  const int lq   = tid & 3;         // 16 floats each

  f32x4 acc[4];
#pragma unroll
  for (int nt = 0; nt < 4; ++nt) acc[nt] = (f32x4){0.f, 0.f, 0.f, 0.f};

  for (int s = 0; s < kchunk; s += 64) {
    const int kk = k0 + s;
#pragma unroll
    for (int c = 0; c < 4; ++c) {
      const int col = lq * 16 + c * 4;
      float4 xv = *(const float4*)&x [(size_t)(t0 + lrow) * HID + kk + col];
      float4 wv = *(const float4*)&wg[(size_t)lrow * HID + kk + col];
      short4 p0, p1, p2;
      cvt3(xv.x, p0.x, p1.x, p2.x);  cvt3(xv.y, p0.y, p1.y, p2.y);
      cvt3(xv.z, p0.z, p1.z, p2.z);  cvt3(xv.w, p0.w, p1.w, p2.w);
      *(short4*)&XA[0][lrow][col] = p0;
      *(short4*)&XA[1][lrow][col] = p1;
      *(short4*)&XA[2][lrow][col] = p2;
      cvt3(wv.x, p0.x, p1.x, p2.x);  cvt3(wv.y, p0.y, p1.y, p2.y);
      cvt3(wv.z, p0.z, p1.z, p2.z);  cvt3(wv.w, p0.w, p1.w, p2.w);
      *(short4*)&WB[0][lrow][col] = p0;
      *(short4*)&WB[1][lrow][col] = p1;
      *(short4*)&WB[2][lrow][col] = p2;
    }
    __syncthreads();
#pragma unroll
    for (int kc = 0; kc < 64; kc += 32) {
      short8 a0 = *(const short8*)&XA[0][w * 16 + m][kc + q * 8];
      short8 a1 = *(const short8*)&XA[1][w * 16 + m][kc + q * 8];
      short8 a2 = *(const short8*)&XA[2][w * 16 + m][kc + q * 8];
      if (swap == 0) {
#pragma unroll
        for (int nt = 0; nt < 4; ++nt) {
          short8 b0 = *(const short8*)&WB[0][nt * 16 + m][kc + q * 8];
          short8 b1 = *(const short8*)&WB[1][nt * 16 + m][kc + q * 8];
          short8 b2 = *(const short8*)&WB[2][nt * 16 + m][kc + q * 8];
          acc[nt] = __builtin_amdgcn_mfma_f32_16x16x32_bf16(a0, b0, acc[nt], 0, 0, 0);
          acc[nt] = __builtin_amdgcn_mfma_f32_16x16x32_bf16(a0, b1, acc[nt], 0, 0, 0);
          acc[nt] = __builtin_amdgcn_mfma_f32_16x16x32_bf16(a1, b0, acc[nt], 0, 0, 0);
          acc[nt] = __builtin_amdgcn_mfma_f32_16x16x32_bf16(a0, b2, acc[nt], 0, 0, 0);
          acc[nt] = __builtin_amdgcn_mfma_f32_16x16x32_bf16(a1, b1, acc[nt], 0, 0, 0);
          acc[nt] = __builtin_amdgcn_mfma_f32_16x16x32_bf16(a2, b0, acc[nt], 0, 0, 0);
        }
      } else {
#pragma unroll
        for (int nt = 0; nt < 4; ++nt) {
          short8 b0 = *(const short8*)&WB[0][nt * 16 + m][kc + q * 8];
          short8 b1 = *(const short8*)&WB[1][nt * 16 + m][kc + q * 8];
          short8 b2 = *(const short8*)&WB[2][nt * 16 + m][kc + q * 8];
          acc[nt] = __builtin_amdgcn_mfma_f32_16x16x32_bf16(b0, a0, acc[nt], 0, 0, 0);
          acc[nt] = __builtin_amdgcn_mfma_f32_16x16x32_bf16(b1, a0, acc[nt], 0, 0, 0);
          acc[nt] = __builtin_amdgcn_mfma_f32_16x16x32_bf16(b0, a1, acc[nt], 0, 0, 0);
          acc[nt] = __builtin_amdgcn_mfma_f32_16x16x32_bf16(b2, a0, acc[nt], 0, 0, 0);
          acc[nt] = __builtin_amdgcn_mfma_f32_16x16x32_bf16(b1, a1, acc[nt], 0, 0, 0);
          acc[nt] = __builtin_amdgcn_mfma_f32_16x16x32_bf16(b0, a2, acc[nt], 0, 0, 0);
        }
      }
    }
    __syncthreads();
  }

  double* base = partial + (size_t)blockIdx.y * TOK * NE;
  if (swap == 0) {
    // D: row = q*4+v = token-within-wave-tile, col = m = expert-within-nt
#pragma unroll
    for (int nt = 0; nt < 4; ++nt)
#pragma unroll
      for (int v = 0; v < 4; ++v)
        base[(size_t)(t0 + w * 16 + q * 4 + v) * NE + nt * 16 + m] =
            (double)acc[nt][v];
  } else {
    // D: row = q*4+v = expert-within-nt, col = m = token-within-wave-tile
#pragma unroll
    for (int nt = 0; nt < 4; ++nt)
#pragma unroll
      for (int v = 0; v < 4; ++v)
        base[(size_t)(t0 + w * 16 + m) * NE + nt * 16 + q * 4 + v] =
            (double)acc[nt][v];
  }
}

// ---------------- 1b. verify: sample 512 logits vs exact fp64 dots --------
// tol 1e-3: passes bf16x3 noise (~1e-5), catches layout bugs (O(0.1+)).
// Proven discriminator (R3/R5 trip on bad gemm; R7 pass on good gemm).
__global__ __launch_bounds__(256) void verify_kernel(
    const float* __restrict__ x, const float* __restrict__ wg,
    const double* __restrict__ partial, int nsplit, int* __restrict__ flag) {
  const int gid  = blockIdx.x * blockDim.x + threadIdx.x;
  const int wid  = gid >> 6;          // 0..511
  const int lane = gid & 63;
  const int t = (wid * 521) & (TOK - 1);
  const int e = wid & 63;
  double acc = 0.0;
  for (int k = lane; k < HID; k += 64)
    acc = fma((double)x[(size_t)t * HID + k], (double)wg[(size_t)e * HID + k], acc);
#pragma unroll
  for (int off = 32; off; off >>= 1) acc += __shfl_xor(acc, off);
  if (lane == 0) {
    double got = 0.0;
    for (int p = 0; p < nsplit; ++p)
      got += partial[(size_t)p * TOK * NE + (size_t)t * NE + e];
    if (!(fabs(got - acc) <= 1e-3)) atomicOr(flag, 1);  // NaN-safe
  }
}

// ---------------- 1c. repair: R9's proven fp64 split-K gemm, flag-gated ---
__global__ __launch_bounds__(256) void repair_splitk(
    const float* __restrict__ x, const float* __restrict__ wg,
    double* __restrict__ partial, int kchunk, const int* __restrict__ flag) {
  if (*(volatile const int*)flag == 0) return;
  __shared__ float xs[16][68];
  __shared__ float wsh[64][68];
  const int tid = threadIdx.x;
  const int t0  = blockIdx.x * 16;
  const int k0  = blockIdx.y * kchunk;
  const int tok = tid & 15;
  const int eg  = tid >> 4;
  const int lrow = tid >> 4;
  const int lq   = tid & 15;
  double acc[4] = {0.0, 0.0, 0.0, 0.0};

  for (int s = 0; s < kchunk; s += 64) {
    const int kk = k0 + s;
    {
      float4 v = *(const float4*)&x[(size_t)(t0 + lrow) * HID + kk + lq * 4];
      *(float4*)&xs[lrow][lq * 4] = v;
    }
#pragma unroll
    for (int it = 0; it < 4; ++it) {
      int r = it * 16 + lrow;
      float4 v = *(const float4*)&wg[(size_t)r * HID + kk + lq * 4];
      *(float4*)&wsh[r][lq * 4] = v;
    }
    __syncthreads();
#pragma unroll
    for (int kc = 0; kc < 64; kc += 4) {
      float4 xv = *(const float4*)&xs[tok][kc];
#pragma unroll
      for (int j = 0; j < 4; ++j) {
        float4 wv = *(const float4*)&wsh[eg * 4 + j][kc];
        acc[j] = fma((double)xv.x, (double)wv.x, acc[j]);
        acc[j] = fma((double)xv.y, (double)wv.y, acc[j]);
        acc[j] = fma((double)xv.z, (double)wv.z, acc[j]);
        acc[j] = fma((double)xv.w, (double)wv.w, acc[j]);
      }
    }
    __syncthreads();
  }
  double* base = partial + (size_t)blockIdx.y * TOK * NE;
#pragma unroll
  for (int j = 0; j < 4; ++j)
    base[(size_t)(t0 + tok) * NE + eg * 4 + j] = acc[j];
}

// ---------------- 2. softmax + top-8 per token (one wave64/token) ----------
__global__ __launch_bounds__(256) void topk_kernel(
    const double* __restrict__ partial, int nsplit,
    int* __restrict__ idx_kt, float* __restrict__ w_kt) {
  const int gid  = blockIdx.x * blockDim.x + threadIdx.x;
  const int t    = gid >> 6;
  const int lane = gid & 63;

  double v = 0.0;
  for (int p = 0; p < nsplit; ++p)
    v += partial[(size_t)p * TOK * NE + (size_t)t * NE + lane];

  double m = v;
#pragma unroll
  for (int off = 32; off; off >>= 1) {
    double o = __shfl_xor(m, off);
    m = o > m ? o : m;
  }
  double g = exp(v - m);
  double s = g;
#pragma unroll
  for (int off = 32; off; off >>= 1) s += __shfl_xor(s, off);
  double gate = g / s;

  float key = (float)gate;    // fp32-rounded key, tie -> lower index
  double ssel = 0.0;
  int my_k = -1;
#pragma unroll
  for (int k = 0; k < NK; ++k) {
    float bv = key;
    int   bi = lane;
#pragma unroll
    for (int off = 32; off; off >>= 1) {
      float ov = __shfl_xor(bv, off);
      int   oi = __shfl_xor(bi, off);
      if (ov > bv || (ov == bv && oi < bi)) { bv = ov; bi = oi; }
    }
    ssel += __shfl(gate, bi);
    if (lane == bi) { my_k = k; key = -1.0f; }
  }
  double gs = ssel;
  const double eps = (double)1.1920929e-07f;
  if (gs < eps) gs = eps;

  if (my_k >= 0) {
    idx_kt[my_k * TOK + t] = lane;
    w_kt [my_k * TOK + t] = (float)(gate / gs);
  }
}

// ---------------- 3. fused rank + scatter ------------------------------
__global__ __launch_bounds__(1024) void rank_scatter(
    const int* __restrict__ idx_kt, const float* __restrict__ w_kt,
    float* __restrict__ out, int C) {
  const int e    = blockIdx.x;
  const int tid  = threadIdx.x;
  const int lane = tid & 63;
  const int w    = tid >> 6;          // 0..15
  __shared__ int wt[16];
  int running = 0;
  const unsigned long long below = (1ull << lane) - 1ull;

  for (int i0 = 0; i0 < NK * TOK; i0 += 1024) {
    const int i = i0 + tid;
    const bool mhit = (idx_kt[i] == e);
    unsigned long long mask = __ballot(mhit);
    if (lane == 0) wt[w] = __popcll(mask);
    __syncthreads();
    int woff = 0, tot = 0;
#pragma unroll
    for (int j = 0; j < 16; ++j) {
      int c = wt[j];
      tot += c;
      if (j < w) woff += c;
    }
    if (mhit) {
      const int c = running + woff + __popcll(mask & below);
      if (c < C) {
        const int t = i & (TOK - 1);
        size_t off = ((size_t)t * NE + e) * (size_t)C + (size_t)c;
        out[off] = w_kt[i];                          // combine_weights
        out[(size_t)TOK * NE * C + off] = 1.0f;      // dispatch_mask
      }
    }
    running += tot;
    __syncthreads();
  }
}

extern "C" void kernel_launch(void* const* d_in, const int* in_sizes, int n_in,
                              void* d_out, int out_size, void* d_ws, size_t ws_size,
                              hipStream_t stream) {
  const float* x  = (const float*)d_in[0];   // [4096,4096]
  const float* wg = (const float*)d_in[1];   // [64,4096]
  float* out = (float*)d_out;

  const int C = out_size / (2 * TOK * NE);   // capacity from output size

  const size_t slab = (size_t)TOK * NE * sizeof(double);   // 2 MB per partial
  const size_t tail = 2 * (size_t)NK * TOK * sizeof(int);  // idx + w
  int nsplit = 8;
  while (nsplit > 1 && (size_t)nsplit * slab + tail + 128 > ws_size) nsplit >>= 1;
  const int kchunk = HID / nsplit;

  char* ws = (char*)d_ws;
  double* partial = (double*)ws;
  int*    idx_kt  = (int*)  (ws + (size_t)nsplit * slab);
  float*  w_kt    = (float*)(ws + (size_t)nsplit * slab + (size_t)NK * TOK * 4);
  int*    flagA   = (int*)  (ws + (size_t)nsplit * slab + tail);
  int*    flagB   = flagA + 1;

  // zero the 4.76 GB output (poisoned 0xAA before every timed launch)
  hipMemsetAsync(d_out, 0, (size_t)out_size * sizeof(float), stream);

  dim3 bgrid(TOK / 64, nsplit);   // 64 x 8 = 512 blocks
  dim3 rgrid(TOK / 16, nsplit);   // repair: 256 x 8
  // V0: mfma(xf, wf); clears both flags
  gemm_bf16x3  <<<bgrid, 256, 0, stream>>>(x, wg, partial, kchunk, 0,
                                           nullptr, flagA, flagB);
  verify_kernel<<<128, 256, 0, stream>>>(x, wg, partial, nsplit, flagA);
  // V1: mfma(wf, xf), transposed store; only runs if V0 failed
  gemm_bf16x3  <<<bgrid, 256, 0, stream>>>(x, wg, partial, kchunk, 1,
                                           flagA, nullptr, nullptr);
  verify_kernel<<<128, 256, 0, stream>>>(x, wg, partial, nsplit, flagB);
  // final net: proven fp64 split-K, only if both MFMA variants failed
  repair_splitk<<<rgrid, 256, 0, stream>>>(x, wg, partial, kchunk, flagB);
  topk_kernel  <<<TOK * 64 / 256, 256, 0, stream>>>(partial, nsplit, idx_kt, w_kt);
  rank_scatter <<<NE, 1024, 0, stream>>>(idx_kt, w_kt, out, C);
}